// Round 10
// baseline (453.851 us; speedup 1.0000x reference)
//
#include <hip/hip_runtime.h>
#include <hip/hip_cooperative_groups.h>
#include <math.h>

namespace cg = cooperative_groups;

#define Tdim 1024
#define Hh   64

#if __has_builtin(__builtin_amdgcn_exp2f)
#define EXP2(x) __builtin_amdgcn_exp2f(x)
#else
#define EXP2(x) exp2f(x)
#endif

// (1/(sqrt(2)*0.8)) * log2(e) — folded into Q so attention uses exp2 directly
__device__ __constant__ float kQScale = 0.8838834764831844f * 1.4426950408889634f;

// ---------------------------------------------------------------------------
// Fused cooperative kernel: qkv_proj -> grid.sync -> attn -> grid.sync ->
// out_proj. Grid-stride item loops make any grid size correct; launcher
// clamps grid to queried co-resident capacity (<= 1024).
// LDS: phase1 26.6K | phase2 16K | phase3 17.2K  (static union 26624 B).
// ---------------------------------------------------------------------------
__global__ __launch_bounds__(256, 4) void fused(
    const float* __restrict__ x,  const float* __restrict__ Wq,
    const float* __restrict__ Wk, const float* __restrict__ Wv,
    const float* __restrict__ Wo,
    float* __restrict__ Q, float* __restrict__ KV,
    float* __restrict__ O, float* __restrict__ out)
{
    __shared__ __align__(16) unsigned char smem[26624];
    cg::grid_group grid = cg::this_grid();

    const int tid = threadIdx.x;
    const int nb  = gridDim.x;

    // ===================== Phase 1: QKV projection (R5 design) ==============
    // 384 items: rowg = item & 127 (16 rows), mat = item >> 7.
    for (int item = blockIdx.x; item < 384; item += nb) {
        __syncthreads();   // protect LDS reuse across iterations/phases
        float (*xs)[128] = reinterpret_cast<float(*)[128]>(smem);
        float (*Wch)[36] = reinterpret_cast<float(*)[36]>(smem + 8192);

        const int row0 = (item & 127) * 16;
        const int w    = item >> 7;          // 0=Q 1=K 2=V

        {
            const float4* xg = reinterpret_cast<const float4*>(x + (size_t)row0 * 128);
            reinterpret_cast<float4*>(&xs[0][0])[tid]       = xg[tid];
            reinterpret_cast<float4*>(&xs[0][0])[tid + 256] = xg[tid + 256];
        }

        const float* W = (w == 0) ? Wq : (w == 1) ? Wk : Wv;

        const int j0 = tid & 31;
        const int r0 = (tid >> 5) << 1;

        float acc[2][4];
#pragma unroll
        for (int r = 0; r < 2; ++r)
#pragma unroll
            for (int c = 0; c < 4; ++c) acc[r][c] = 0.f;

        for (int ch = 0; ch < 4; ++ch) {
            __syncthreads();
#pragma unroll
            for (int s = 0; s < 4; ++s) {
                const int idx  = tid + s * 256;
                const int rowW = idx >> 3;
                const int c4   = idx & 7;
                *reinterpret_cast<float4*>(&Wch[rowW][c4 * 4]) =
                    reinterpret_cast<const float4*>(W + (size_t)rowW * 128 + ch * 32)[c4];
            }
            __syncthreads();

#pragma unroll
            for (int c = 0; c < 8; ++c) {
                const float4 w0 = *reinterpret_cast<const float4*>(&Wch[j0      ][c * 4]);
                const float4 w1 = *reinterpret_cast<const float4*>(&Wch[j0 + 32 ][c * 4]);
                const float4 w2 = *reinterpret_cast<const float4*>(&Wch[j0 + 64 ][c * 4]);
                const float4 w3 = *reinterpret_cast<const float4*>(&Wch[j0 + 96 ][c * 4]);
#pragma unroll
                for (int r = 0; r < 2; ++r) {
                    const float4 xv = *reinterpret_cast<const float4*>(&xs[r0 + r][ch * 32 + c * 4]);
                    acc[r][0] = fmaf(xv.x, w0.x, fmaf(xv.y, w0.y, fmaf(xv.z, w0.z, fmaf(xv.w, w0.w, acc[r][0]))));
                    acc[r][1] = fmaf(xv.x, w1.x, fmaf(xv.y, w1.y, fmaf(xv.z, w1.z, fmaf(xv.w, w1.w, acc[r][1]))));
                    acc[r][2] = fmaf(xv.x, w2.x, fmaf(xv.y, w2.y, fmaf(xv.z, w2.z, fmaf(xv.w, w2.w, acc[r][2]))));
                    acc[r][3] = fmaf(xv.x, w3.x, fmaf(xv.y, w3.y, fmaf(xv.z, w3.z, fmaf(xv.w, w3.w, acc[r][3]))));
                }
            }
        }

#pragma unroll
        for (int r = 0; r < 2; ++r) {
            const int row = row0 + r0 + r;
            const int bb  = row >> 10;
            const int t   = row & 1023;
#pragma unroll
            for (int jj = 0; jj < 4; ++jj) {
                const int j = j0 + jj * 32;
                const float v = acc[r][jj];
                if (w == 0) {
                    Q[(size_t)row * 128 + j] = v * kQScale;
                } else {
                    const int h  = j >> 1, dh = j & 1;
                    const int bh = bb * Hh + h;
                    KV[((size_t)bh * Tdim + t) * 4 + ((w == 1) ? dh : 2 + dh)] = v;
                }
            }
        }
    }

    grid.sync();

    // ===================== Phase 2: attention (R5 balanced + prefetch) ======
    // 1024 items: c = item & 7, bh = item >> 3.
    for (int item = blockIdx.x; item < 1024; item += nb) {
        __syncthreads();
        float4* KVs = reinterpret_cast<float4*>(smem);   // 16 KB
        const int c     = item & 7;
        const int bh    = item >> 3;
        const int lowb  = c * 64;
        const int highb = (15 - c) * 64;
        const int nk    = highb + 64;

        const float4* KVg = reinterpret_cast<const float4*>(KV) + (size_t)bh * Tdim;
        for (int i = tid; i < nk; i += 256) KVs[i] = KVg[i];
        __syncthreads();

        const int sub = tid & 7;
        const int g   = tid >> 3;
        const int lq  = lowb + 2 * g;
        const int hq  = highb + 62 - 2 * g;   // lq + hq = 1022 (balance)
        const int b   = bh >> 6, h = bh & 63;

        const float* Qb = Q + (size_t)b * (Tdim * 128) + h * 2;
        float2 q[4];
        q[0] = *reinterpret_cast<const float2*>(Qb + (size_t)(lq    ) * 128);
        q[1] = *reinterpret_cast<const float2*>(Qb + (size_t)(lq + 1) * 128);
        q[2] = *reinterpret_cast<const float2*>(Qb + (size_t)(hq    ) * 128);
        q[3] = *reinterpret_cast<const float2*>(Qb + (size_t)(hq + 1) * 128);

        float l[4]  = {0.f, 0.f, 0.f, 0.f};
        float a0[4] = {0.f, 0.f, 0.f, 0.f};
        float a1[4] = {0.f, 0.f, 0.f, 0.f};

        auto upd = [&](int i, const float4 kv) {
            const float p = EXP2(fmaf(q[i].x, kv.x, q[i].y * kv.y));
            l[i] += p;
            a0[i] = fmaf(p, kv.z, a0[i]);
            a1[i] = fmaf(p, kv.w, a1[i]);
        };

        // phase A: keys [0, lq) — all 4 queries, 2-stage prefetch
        {
            int k = sub;
            if (k < lq) {
                float4 kv = KVs[k];
                for (k += 8; k < lq; k += 8) {
                    const float4 nxt = KVs[k];
                    upd(0, kv); upd(1, kv); upd(2, kv); upd(3, kv);
                    kv = nxt;
                }
                upd(0, kv); upd(1, kv); upd(2, kv); upd(3, kv);
            }
        }
        // low diagonal
        if (sub <= 1) {
            const float4 kv = KVs[lq + sub];
            if (sub == 0) upd(0, kv);
            upd(1, kv);
        }
        // phase B: keys [lq.., hq) — high queries, 2-stage prefetch
        {
            int k = (lq & ~7) + sub; if (k < lq) k += 8;
            if (k < hq) {
                float4 kv = KVs[k];
                for (k += 8; k < hq; k += 8) {
                    const float4 nxt = KVs[k];
                    upd(2, kv); upd(3, kv);
                    kv = nxt;
                }
                upd(2, kv); upd(3, kv);
            }
        }
        // high diagonal
        if (sub <= 1) {
            const float4 kv = KVs[hq + sub];
            if (sub == 0) upd(2, kv);
            upd(3, kv);
        }

#pragma unroll
        for (int i = 0; i < 4; ++i) {
            l[i]  += __shfl_xor(l[i], 1);  l[i]  += __shfl_xor(l[i], 2);  l[i]  += __shfl_xor(l[i], 4);
            a0[i] += __shfl_xor(a0[i], 1); a0[i] += __shfl_xor(a0[i], 2); a0[i] += __shfl_xor(a0[i], 4);
            a1[i] += __shfl_xor(a1[i], 1); a1[i] += __shfl_xor(a1[i], 2); a1[i] += __shfl_xor(a1[i], 4);
        }

        if (sub == 0) {
            float* Ob = O + (size_t)b * (Tdim * 128) + h * 2;
#pragma unroll
            for (int i = 0; i < 4; ++i) {
                const int row = (i < 2) ? (lq + i) : (hq + i - 2);
                const float rl = 1.0f / l[i];
                *reinterpret_cast<float2*>(Ob + (size_t)row * 128) =
                    make_float2(a0[i] * rl, a1[i] * rl);
            }
        }
    }

    grid.sync();

    // ===================== Phase 3: output projection (R8 design) ===========
    // 256 items: rowg = item >> 1 (16 rows), col half = item & 1.
    for (int item = blockIdx.x; item < 256; item += nb) {
        __syncthreads();
        float (*xs)[128]  = reinterpret_cast<float(*)[128]>(smem);
        float (*Wch)[36]  = reinterpret_cast<float(*)[36]>(smem + 8192);

        const int row0 = (item >> 1) * 16;
        const int H    = item & 1;

        {
            const float4* xg = reinterpret_cast<const float4*>(O + (size_t)row0 * 128);
            reinterpret_cast<float4*>(&xs[0][0])[tid]       = xg[tid];
            reinterpret_cast<float4*>(&xs[0][0])[tid + 256] = xg[tid + 256];
        }

        const int j0 = tid & 31;
        const int r0 = (tid >> 5) << 1;

        float acc[2][2] = {{0.f, 0.f}, {0.f, 0.f}};

        for (int ch = 0; ch < 4; ++ch) {
            __syncthreads();
#pragma unroll
            for (int s2 = 0; s2 < 2; ++s2) {
                const int idx  = tid + s2 * 256;
                const int rowW = idx >> 3;
                const int c4   = idx & 7;
                *reinterpret_cast<float4*>(&Wch[rowW][c4 * 4]) =
                    reinterpret_cast<const float4*>(
                        Wo + (size_t)(H * 64 + rowW) * 128 + ch * 32)[c4];
            }
            __syncthreads();

#pragma unroll
            for (int cc = 0; cc < 8; ++cc) {
                const float4 w0 = *reinterpret_cast<const float4*>(&Wch[j0     ][cc * 4]);
                const float4 w1 = *reinterpret_cast<const float4*>(&Wch[j0 + 32][cc * 4]);
#pragma unroll
                for (int r = 0; r < 2; ++r) {
                    const float4 xv = *reinterpret_cast<const float4*>(&xs[r0 + r][ch * 32 + cc * 4]);
                    acc[r][0] = fmaf(xv.x, w0.x, fmaf(xv.y, w0.y, fmaf(xv.z, w0.z, fmaf(xv.w, w0.w, acc[r][0]))));
                    acc[r][1] = fmaf(xv.x, w1.x, fmaf(xv.y, w1.y, fmaf(xv.z, w1.z, fmaf(xv.w, w1.w, acc[r][1]))));
                }
            }
        }

#pragma unroll
        for (int r = 0; r < 2; ++r) {
            const int row = row0 + r0 + r;
            out[(size_t)row * 128 + H * 64 + j0]      = acc[r][0];
            out[(size_t)row * 128 + H * 64 + j0 + 32] = acc[r][1];
        }
    }
}

extern "C" void kernel_launch(void* const* d_in, const int* in_sizes, int n_in,
                              void* d_out, int out_size, void* d_ws, size_t ws_size,
                              hipStream_t stream) {
    const float* x  = (const float*)d_in[0];
    const float* Wq = (const float*)d_in[1];
    const float* Wk = (const float*)d_in[2];
    const float* Wv = (const float*)d_in[3];
    const float* Wo = (const float*)d_in[4];
    float* out = (float*)d_out;

    // ws layout (floats): Q 1MB | KV 2MB | O 1MB
    float* ws = (float*)d_ws;
    float* Q  = ws;
    float* KV = ws + 262144;
    float* O  = ws + 786432;

    // Clamp grid to the device's cooperative co-residency capacity.
    // Pure host-side query: deterministic, graph-capture-safe.
    int maxB = 0;
    (void)hipOccupancyMaxActiveBlocksPerMultiprocessor(
        &maxB, (const void*)fused, 256, 0);
    int grid = 256;                 // always co-resident fallback
    if (maxB >= 4)      grid = 1024;
    else if (maxB >= 2) grid = 512; // divides 384? no — grid-stride handles it;
                                    // divides 1024 & 256 evenly, 384 -> 1.5 avg
    void* args[] = {(void*)&x, (void*)&Wq, (void*)&Wk, (void*)&Wv, (void*)&Wo,
                    (void*)&Q, (void*)&KV, (void*)&O, (void*)&out};
    hipLaunchCooperativeKernel((const void*)fused, dim3(grid), dim3(256),
                               args, 0, stream);
}